// Round 6
// baseline (273.928 us; speedup 1.0000x reference)
//
#include <hip/hip_runtime.h>

// ---------------------------------------------------------------------------
// AbsSeriesSoap: p[i,k,l] and dp[i,k,l,j,x] for N points.
// LMAX=6, NMAX=5, RC=3.0, UNIT=RC/3=1.0 (identity scaling).
// out = [ p (6*6*7=252 floats) | dp (6*6*7*N*3 floats) ]
// k_dp: LDS-staged cooperative full-line dwordx4 stores + VGPR-slimmed math:
//  - d/dx (x+iy)^m = m(x+iy)^{m-1}  => no Ax/Ay/Bx/By arrays (-28 VGPR)
//  - Euler homogeneity: Pr = ((l-m)Pi - z*Pz)/(2 r^2) => no Pr recursion (-14)
//  - dfi[]+unit-vector instead of dfx/dfy/dfz[]            (-9)
// __launch_bounds__(256,4) targets 4 waves/SIMD (16 waves/CU, 4 blocks/CU).
// ---------------------------------------------------------------------------

#define LMAXV 6
#define NSZ 6          // NMAX+1
#define RCV 3.0f

typedef float float4v __attribute__((ext_vector_type(4)));

// Barrier that waits only on LDS ops (global stores stay in flight).
__device__ __forceinline__ void barrier_lds() {
    asm volatile("s_waitcnt lgkmcnt(0)" ::: "memory");
    __builtin_amdgcn_sched_barrier(0);
    __builtin_amdgcn_s_barrier();
}

// ---- compile-time tables ---------------------------------------------------
constexpr double csqrt_(double x) {
    double y = x > 1.0 ? x : 1.0;
    for (int i = 0; i < 100; ++i) y = 0.5 * (y + x / y);
    return y;
}
constexpr double factd_(int n) { double r = 1.0; for (int i = 2; i <= n; ++i) r *= i; return r; }
constexpr double PI_D = 3.14159265358979323846;
struct CnlT { float v[7][7]; };
constexpr CnlT make_cnl_() {
    CnlT t{};
    for (int l = 0; l <= 6; ++l)
        for (int m = 0; m <= 6; ++m)
            t.v[l][m] = (m <= l)
                ? (float)csqrt_((2.0 * l + 1.0) / (4.0 * PI_D) * factd_(l - m) / factd_(l + m))
                : 0.0f;
    return t;
}
__device__ constexpr CnlT CNL = make_cnl_();
__device__ constexpr float DFACT[7] = {1.f, 1.f, 3.f, 15.f, 105.f, 945.f, 10395.f}; // (2l-1)!!
struct IctT { float v[7][7]; };
constexpr IctT make_ict_() {
    IctT t{};
    for (int l = 0; l <= 6; ++l)
        for (int m = 0; m <= 6; ++m)
            t.v[l][m] = (l > m) ? (float)(1.0 / (double)(l - m)) : 1.0f;
    return t;
}
__device__ constexpr IctT ICT = make_ict_();

// ---- kernel 0: zero the c workspace (294 floats) ---------------------------
__global__ void k_zero(float* __restrict__ cws) {
    int t = blockIdx.x * blockDim.x + threadIdx.x;
    if (t < NSZ * 49) cws[t] = 0.0f;
}

// ---- kernel 1: c[i,a,b] = sum_j f[i,j] * Y[a,b,j] --------------------------
__global__ __launch_bounds__(256) void k_creduce(const float* __restrict__ coo,
                                                 float* __restrict__ cws, int N) {
    const int i_rad = blockIdx.y;
    float acc[7][7];
#pragma unroll
    for (int a = 0; a < 7; ++a)
#pragma unroll
        for (int b = 0; b < 7; ++b) acc[a][b] = 0.0f;

    const int stride = gridDim.x * blockDim.x;
    for (int j = blockIdx.x * blockDim.x + threadIdx.x; j < N; j += stride) {
        float x = coo[3 * j + 0], y = coo[3 * j + 1], z = coo[3 * j + 2];
        float r2 = x * x + y * y + z * z;
        float dn = sqrtf(r2);
        float tt = 1.0f - dn * (1.0f / RCV);
        float r  = (dn < RCV) ? tt * tt : 0.0f;
        float fi = r;
        for (int q = 0; q < i_rad; ++q) fi *= r2;   // f_i = r * (d^2)^i

        float Av[7], Bv[7];
        Av[0] = 1.0f; Bv[0] = 0.0f;
#pragma unroll
        for (int m = 1; m <= 6; ++m) {
            Av[m] = x * Av[m - 1] - y * Bv[m - 1];
            Bv[m] = x * Bv[m - 1] + y * Av[m - 1];
        }

        float P1[7], P2[7];
#pragma unroll
        for (int l = 0; l <= 6; ++l) {
            float PC[7];
#pragma unroll
            for (int mm = 0; mm <= l; ++mm) {
                float pv;
                if (mm == l)            pv = DFACT[l];
                else if (mm == l - 1)   pv = (float)(2 * l - 1) * z * P1[mm];
                else {
                    float a = (float)(2 * l - 1), b = (float)(l + mm - 1);
                    pv = (a * z * P1[mm] - b * r2 * P2[mm]) * (1.0f / (float)(l - mm));
                }
                PC[mm] = pv;
                float base = fi * CNL.v[l][mm] * pv;
                acc[l][l - mm] += base * Av[mm];
                if (mm >= 1) acc[l - mm][l] += base * Bv[mm];
            }
#pragma unroll
            for (int mm = 0; mm <= l; ++mm) { P2[mm] = P1[mm]; P1[mm] = PC[mm]; }
        }
    }

    __shared__ float sblk[49];
    if (threadIdx.x < 49) sblk[threadIdx.x] = 0.0f;
    __syncthreads();
    const int lane = threadIdx.x & 63;
#pragma unroll
    for (int a = 0; a < 7; ++a)
#pragma unroll
        for (int b = 0; b < 7; ++b) {
            float v = acc[a][b];
            v += __shfl_down(v, 32);
            v += __shfl_down(v, 16);
            v += __shfl_down(v, 8);
            v += __shfl_down(v, 4);
            v += __shfl_down(v, 2);
            v += __shfl_down(v, 1);
            if (lane == 0) atomicAdd(&sblk[a * 7 + b], v);
        }
    __syncthreads();
    if (threadIdx.x < 49) atomicAdd(&cws[i_rad * 49 + threadIdx.x], sblk[threadIdx.x]);
}

// ---- kernel 2: p[i,k,l] (252 values) ---------------------------------------
__global__ void k_p(const float* __restrict__ cws, float* __restrict__ out) {
    int t = threadIdx.x;
    if (t >= 252) return;
    int i = t / 42, k = (t / 7) % 6, l = t % 7;
    const float* ci = cws + i * 49;
    const float* ck = cws + k * 49;
    float s = 0.0f;
    for (int mm = 0; mm <= l; ++mm) {
        float w = (mm == 0) ? 1.0f : 2.0f;
        s += w * ci[l * 7 + (l - mm)] * ck[l * 7 + (l - mm)];
        if (mm >= 1) s += 2.0f * ci[(l - mm) * 7 + l] * ck[(l - mm) * 7 + l];
    }
    out[t] = s;
}

// ---- kernel 3: dp[i,k,l,j,x] — slim registers + LDS-staged stores ----------
__global__ __launch_bounds__(256, 4) void k_dp(const float* __restrict__ coo,
                                               const float* __restrict__ cws,
                                               float* __restrict__ out, int N,
                                               int nblk) {
    __shared__ float sRe[7][7][6];
    __shared__ float sIm[7][7][6];
    __shared__ float stage[12][768];   // 12 slices x 256 pts x 3 floats = 36KB

    for (int s = threadIdx.x; s < 294; s += blockDim.x) {
        int k = s % 6; int lm = s / 6; int l = lm / 7; int mm = lm % 7;
        float re = 0.0f, im = 0.0f;
        if (mm <= l)            re = ((mm == 0) ? 1.0f : 2.0f) * cws[k * 49 + l * 7 + (l - mm)];
        if (mm >= 1 && mm <= l) im = 2.0f * cws[k * 49 + (l - mm) * 7 + l];
        sRe[l][mm][k] = re;
        sIm[l][mm][k] = im;
    }
    __syncthreads();

    // bijective XCD-chunk remap (m204)
    int chunk;
    {
        const int b = blockIdx.x;
        const int q = nblk >> 3, rr = nblk & 7;
        const int xcd = b & 7, idx = b >> 3;
        chunk = (xcd < rr ? xcd * (q + 1) : rr * (q + 1) + (xcd - rr) * q) + idx;
    }
    const int j0 = chunk * 256;
    const int jj = min(j0 + (int)threadIdx.x, N - 1);   // clamp; all threads stay alive

    const float x = coo[3 * jj + 0], y = coo[3 * jj + 1], z = coo[3 * jj + 2];
    const float r2 = x * x + y * y + z * z;
    const float dn = sqrtf(r2);
    const float invd = 1.0f / dn;
    const float inv2r2 = 0.5f / r2;
    const float tt = 1.0f - dn * (1.0f / RCV);
    const bool  ins = dn < RCV;
    const float r  = ins ? tt * tt : 0.0f;
    const float dr = ins ? (-2.0f / RCV) * tt : 0.0f;
    const float ux = x * invd, uy = y * invd, uz = z * invd;

    float f[NSZ], dfi[NSZ];
    {
        float p2 = 1.0f;
#pragma unroll
        for (int i = 0; i < NSZ; ++i) {
            f[i] = r * p2;
            dfi[i] = p2 * (dr + (float)(2 * i) * r * invd);
            p2 *= r2;
        }
    }

    // (x+iy)^m (values only; gradients via m*(x+iy)^{m-1} analyticity)
    float Av[7], Bv[7];
    Av[0] = 1.0f; Bv[0] = 0.0f;
#pragma unroll
    for (int m = 1; m <= 6; ++m) {
        Av[m] = x * Av[m - 1] - y * Bv[m - 1];
        Bv[m] = x * Bv[m - 1] + y * Av[m - 1];
    }

    // Legendre state: value + dz only (dr2 via Euler identity)
    float P1v[7], P1z[7], P2v[7], P2z[7];
#pragma unroll
    for (int mm = 0; mm < 7; ++mm) {
        P1v[mm] = 0.f; P1z[mm] = 0.f; P2v[mm] = 0.f; P2z[mm] = 0.f;
    }

    const uint32_t sliceB = (uint32_t)N * 12u;          // bytes per (i,k,l) slice
    const uint32_t j0b    = (uint32_t)j0 * 12u;
    const uint32_t remB   = (uint32_t)(min(256, N - j0)) * 12u;
    char* const outB = (char*)out;
    const int tid3 = (int)threadIdx.x * 3;

#pragma unroll 1
    for (int l = 0; l <= LMAXV; ++l) {
        float S[NSZ], Tx[NSZ], Ty[NSZ], Tz[NSZ];
#pragma unroll
        for (int k = 0; k < NSZ; ++k) { S[k] = 0.0f; Tx[k] = 0.0f; Ty[k] = 0.0f; Tz[k] = 0.0f; }

        const float lf  = (float)l;
        const float a2l = 2.0f * lf - 1.0f;
        const float dfl = DFACT[l];

#pragma unroll
        for (int mm = 0; mm <= 6; ++mm) {
            if (mm <= l) {   // uniform scalar branch
                const float b  = lf + (float)(mm - 1);
                const float ic = ICT.v[l][mm];
                float pv = (a2l * z * P1v[mm] - b * r2 * P2v[mm]) * ic;
                float pz = (a2l * (P1v[mm] + z * P1z[mm]) - b * r2 * P2z[mm]) * ic;
                if (mm == l) pv = dfl;
                // Euler: z*Pz + 2 r2*Pr = (l-mm)*Pv  =>  Pr = ((l-mm)Pv - z Pz)/(2 r2)
                const float pr = ((lf - (float)mm) * pv - z * pz) * inv2r2;
                P2v[mm] = P1v[mm]; P2z[mm] = P1z[mm];
                P1v[mm] = pv; P1z[mm] = pz;

                const float c0  = CNL.v[l][mm];
                const float cp  = c0 * pv;
                const float prx = c0 * 2.0f * pr;
                const float gz  = c0 * pz + prx * z;
                const float pmv = cp * (float)mm;      // cp * m  (analyticity factor)
                const int  mp  = (mm > 0) ? mm - 1 : 0;

                const float ReV = cp * Av[mm];
                const float ReX = prx * x * Av[mm] + pmv * Av[mp];
                const float ReG = prx * y * Av[mm] - pmv * Bv[mp];
                const float ReZ = gz * Av[mm];
#pragma unroll
                for (int k = 0; k < NSZ; ++k) {
                    const float cc = sRe[l][mm][k];
                    S[k]  += cc * ReV;
                    Tx[k] += cc * ReX;
                    Ty[k] += cc * ReG;
                    Tz[k] += cc * ReZ;
                }
                if (mm >= 1) {
                    const float ImV = cp * Bv[mm];
                    const float ImX = prx * x * Bv[mm] + pmv * Bv[mp];
                    const float ImG = prx * y * Bv[mm] + pmv * Av[mp];
                    const float ImZ = gz * Bv[mm];
#pragma unroll
                    for (int k = 0; k < NSZ; ++k) {
                        const float cc = sIm[l][mm][k];
                        S[k]  += cc * ImV;
                        Tx[k] += cc * ImX;
                        Ty[k] += cc * ImG;
                        Tz[k] += cc * ImZ;
                    }
                }
            }
        }

        // stage + cooperative store, 3 groups of 12 slices
        const uint32_t lbase = 1008u + (uint32_t)l * sliceB + j0b;
        const uint32_t ikstride = 7u * sliceB;          // (i,k) pair stride in bytes
#pragma unroll
        for (int g = 0; g < 3; ++g) {
#pragma unroll
            for (int sl = 0; sl < 12; ++sl) {
                const int s = g * 12 + sl;
                const int i = s / 6, k = s % 6;
                const int a = (i < k) ? i : k;         // canonical: mirrors bit-identical
                const int c = (i < k) ? k : i;
                const float gg = dfi[a] * S[c] + dfi[c] * S[a];
                const float ox = ux * gg + f[a] * Tx[c] + f[c] * Tx[a];
                const float oy = uy * gg + f[a] * Ty[c] + f[c] * Ty[a];
                const float oz = uz * gg + f[a] * Tz[c] + f[c] * Tz[a];
                stage[sl][tid3 + 0] = ox;
                stage[sl][tid3 + 1] = oy;
                stage[sl][tid3 + 2] = oz;
            }
            barrier_lds();
            // cooperative write: 12 slices x 3072B, 16B lanes (full-line dwordx4)
#pragma unroll
            for (int it = 0; it < 9; ++it) {
                const int slot = it * 256 + (int)threadIdx.x;
                const int sl   = slot / 192;
                const int pos  = slot - sl * 192;
                const uint32_t boff = (uint32_t)pos << 4;
                if (boff < remB) {
                    const int s = g * 12 + sl;
                    float4v v = *(const float4v*)&stage[sl][pos << 2];
                    *(float4v*)(outB + lbase + (uint32_t)s * ikstride + boff) = v;
                }
            }
            barrier_lds();
        }
    }
}

// ---------------------------------------------------------------------------
extern "C" void kernel_launch(void* const* d_in, const int* in_sizes, int n_in,
                              void* d_out, int out_size, void* d_ws, size_t ws_size,
                              hipStream_t stream) {
    const float* coo = (const float*)d_in[0];
    float* out = (float*)d_out;
    float* cws = (float*)d_ws;
    const int N = in_sizes[0] / 3;

    hipLaunchKernelGGL(k_zero, dim3(1), dim3(320), 0, stream, cws);
    hipLaunchKernelGGL(k_creduce, dim3(128, 6), dim3(256), 0, stream, coo, cws, N);
    hipLaunchKernelGGL(k_p, dim3(1), dim3(256), 0, stream, cws, out);
    const int nb = (N + 255) / 256;
    hipLaunchKernelGGL(k_dp, dim3(nb), dim3(256), 0, stream, coo, cws, out, N, nb);
}

// Round 7
// 141.921 us; speedup vs baseline: 1.9301x; 1.9301x over previous
//
#include <hip/hip_runtime.h>

// ---------------------------------------------------------------------------
// AbsSeriesSoap: p[i,k,l] and dp[i,k,l,j,x] for N points.
// LMAX=6, NMAX=5, RC=3.0, UNIT=RC/3=1.0 (identity scaling).
// out = [ p (6*6*7=252 floats) | dp (6*6*7*N*3 floats) ]
// k_dp: LDS-staged cooperative full-line dwordx4 stores + VGPR-slimmed math:
//  - d/dx (x+iy)^m = m(x+iy)^{m-1}  => no Ax/Ay/Bx/By arrays
//  - Euler homogeneity: Pr = ((l-m)Pi - z*Pz)/(2 r^2) => no Pr recursion
//  - dfi[]+unit-vector instead of dfx/dfy/dfz[]
// NOTE: __launch_bounds__(256,4) in R6 forced VGPR=64 -> 308MB of scratch
// spill traffic (FETCH_SIZE counter) and 2x slowdown. Plain (256) here.
// ---------------------------------------------------------------------------

#define LMAXV 6
#define NSZ 6          // NMAX+1
#define RCV 3.0f

typedef float float4v __attribute__((ext_vector_type(4)));

// Barrier that waits only on LDS ops (global stores stay in flight).
__device__ __forceinline__ void barrier_lds() {
    asm volatile("s_waitcnt lgkmcnt(0)" ::: "memory");
    __builtin_amdgcn_sched_barrier(0);
    __builtin_amdgcn_s_barrier();
}

// ---- compile-time tables ---------------------------------------------------
constexpr double csqrt_(double x) {
    double y = x > 1.0 ? x : 1.0;
    for (int i = 0; i < 100; ++i) y = 0.5 * (y + x / y);
    return y;
}
constexpr double factd_(int n) { double r = 1.0; for (int i = 2; i <= n; ++i) r *= i; return r; }
constexpr double PI_D = 3.14159265358979323846;
struct CnlT { float v[7][7]; };
constexpr CnlT make_cnl_() {
    CnlT t{};
    for (int l = 0; l <= 6; ++l)
        for (int m = 0; m <= 6; ++m)
            t.v[l][m] = (m <= l)
                ? (float)csqrt_((2.0 * l + 1.0) / (4.0 * PI_D) * factd_(l - m) / factd_(l + m))
                : 0.0f;
    return t;
}
__device__ constexpr CnlT CNL = make_cnl_();
__device__ constexpr float DFACT[7] = {1.f, 1.f, 3.f, 15.f, 105.f, 945.f, 10395.f}; // (2l-1)!!
struct IctT { float v[7][7]; };
constexpr IctT make_ict_() {
    IctT t{};
    for (int l = 0; l <= 6; ++l)
        for (int m = 0; m <= 6; ++m)
            t.v[l][m] = (l > m) ? (float)(1.0 / (double)(l - m)) : 1.0f;
    return t;
}
__device__ constexpr IctT ICT = make_ict_();

// ---- kernel 0: zero the c workspace (294 floats) ---------------------------
__global__ void k_zero(float* __restrict__ cws) {
    int t = blockIdx.x * blockDim.x + threadIdx.x;
    if (t < NSZ * 49) cws[t] = 0.0f;
}

// ---- kernel 1: c[i,a,b] = sum_j f[i,j] * Y[a,b,j] --------------------------
__global__ __launch_bounds__(256) void k_creduce(const float* __restrict__ coo,
                                                 float* __restrict__ cws, int N) {
    const int i_rad = blockIdx.y;
    float acc[7][7];
#pragma unroll
    for (int a = 0; a < 7; ++a)
#pragma unroll
        for (int b = 0; b < 7; ++b) acc[a][b] = 0.0f;

    const int stride = gridDim.x * blockDim.x;
    for (int j = blockIdx.x * blockDim.x + threadIdx.x; j < N; j += stride) {
        float x = coo[3 * j + 0], y = coo[3 * j + 1], z = coo[3 * j + 2];
        float r2 = x * x + y * y + z * z;
        float dn = sqrtf(r2);
        float tt = 1.0f - dn * (1.0f / RCV);
        float r  = (dn < RCV) ? tt * tt : 0.0f;
        float fi = r;
        for (int q = 0; q < i_rad; ++q) fi *= r2;   // f_i = r * (d^2)^i

        float Av[7], Bv[7];
        Av[0] = 1.0f; Bv[0] = 0.0f;
#pragma unroll
        for (int m = 1; m <= 6; ++m) {
            Av[m] = x * Av[m - 1] - y * Bv[m - 1];
            Bv[m] = x * Bv[m - 1] + y * Av[m - 1];
        }

        float P1[7], P2[7];
#pragma unroll
        for (int l = 0; l <= 6; ++l) {
            float PC[7];
#pragma unroll
            for (int mm = 0; mm <= l; ++mm) {
                float pv;
                if (mm == l)            pv = DFACT[l];
                else if (mm == l - 1)   pv = (float)(2 * l - 1) * z * P1[mm];
                else {
                    float a = (float)(2 * l - 1), b = (float)(l + mm - 1);
                    pv = (a * z * P1[mm] - b * r2 * P2[mm]) * (1.0f / (float)(l - mm));
                }
                PC[mm] = pv;
                float base = fi * CNL.v[l][mm] * pv;
                acc[l][l - mm] += base * Av[mm];
                if (mm >= 1) acc[l - mm][l] += base * Bv[mm];
            }
#pragma unroll
            for (int mm = 0; mm <= l; ++mm) { P2[mm] = P1[mm]; P1[mm] = PC[mm]; }
        }
    }

    __shared__ float sblk[49];
    if (threadIdx.x < 49) sblk[threadIdx.x] = 0.0f;
    __syncthreads();
    const int lane = threadIdx.x & 63;
#pragma unroll
    for (int a = 0; a < 7; ++a)
#pragma unroll
        for (int b = 0; b < 7; ++b) {
            float v = acc[a][b];
            v += __shfl_down(v, 32);
            v += __shfl_down(v, 16);
            v += __shfl_down(v, 8);
            v += __shfl_down(v, 4);
            v += __shfl_down(v, 2);
            v += __shfl_down(v, 1);
            if (lane == 0) atomicAdd(&sblk[a * 7 + b], v);
        }
    __syncthreads();
    if (threadIdx.x < 49) atomicAdd(&cws[i_rad * 49 + threadIdx.x], sblk[threadIdx.x]);
}

// ---- kernel 2: p[i,k,l] (252 values) ---------------------------------------
__global__ void k_p(const float* __restrict__ cws, float* __restrict__ out) {
    int t = threadIdx.x;
    if (t >= 252) return;
    int i = t / 42, k = (t / 7) % 6, l = t % 7;
    const float* ci = cws + i * 49;
    const float* ck = cws + k * 49;
    float s = 0.0f;
    for (int mm = 0; mm <= l; ++mm) {
        float w = (mm == 0) ? 1.0f : 2.0f;
        s += w * ci[l * 7 + (l - mm)] * ck[l * 7 + (l - mm)];
        if (mm >= 1) s += 2.0f * ci[(l - mm) * 7 + l] * ck[(l - mm) * 7 + l];
    }
    out[t] = s;
}

// ---- kernel 3: dp[i,k,l,j,x] — slim registers + LDS-staged stores ----------
__global__ __launch_bounds__(256) void k_dp(const float* __restrict__ coo,
                                            const float* __restrict__ cws,
                                            float* __restrict__ out, int N,
                                            int nblk) {
    __shared__ float sRe[7][7][6];
    __shared__ float sIm[7][7][6];
    __shared__ float stage[12][768];   // 12 slices x 256 pts x 3 floats = 36KB

    for (int s = threadIdx.x; s < 294; s += blockDim.x) {
        int k = s % 6; int lm = s / 6; int l = lm / 7; int mm = lm % 7;
        float re = 0.0f, im = 0.0f;
        if (mm <= l)            re = ((mm == 0) ? 1.0f : 2.0f) * cws[k * 49 + l * 7 + (l - mm)];
        if (mm >= 1 && mm <= l) im = 2.0f * cws[k * 49 + (l - mm) * 7 + l];
        sRe[l][mm][k] = re;
        sIm[l][mm][k] = im;
    }
    __syncthreads();

    // bijective XCD-chunk remap (m204)
    int chunk;
    {
        const int b = blockIdx.x;
        const int q = nblk >> 3, rr = nblk & 7;
        const int xcd = b & 7, idx = b >> 3;
        chunk = (xcd < rr ? xcd * (q + 1) : rr * (q + 1) + (xcd - rr) * q) + idx;
    }
    const int j0 = chunk * 256;
    const int jj = min(j0 + (int)threadIdx.x, N - 1);   // clamp; all threads stay alive

    const float x = coo[3 * jj + 0], y = coo[3 * jj + 1], z = coo[3 * jj + 2];
    const float r2 = x * x + y * y + z * z;
    const float dn = sqrtf(r2);
    const float invd = 1.0f / dn;
    const float inv2r2 = 0.5f / r2;
    const float tt = 1.0f - dn * (1.0f / RCV);
    const bool  ins = dn < RCV;
    const float r  = ins ? tt * tt : 0.0f;
    const float dr = ins ? (-2.0f / RCV) * tt : 0.0f;
    const float ux = x * invd, uy = y * invd, uz = z * invd;

    float f[NSZ], dfi[NSZ];
    {
        float p2 = 1.0f;
#pragma unroll
        for (int i = 0; i < NSZ; ++i) {
            f[i] = r * p2;
            dfi[i] = p2 * (dr + (float)(2 * i) * r * invd);
            p2 *= r2;
        }
    }

    // (x+iy)^m (values only; gradients via m*(x+iy)^{m-1} analyticity)
    float Av[7], Bv[7];
    Av[0] = 1.0f; Bv[0] = 0.0f;
#pragma unroll
    for (int m = 1; m <= 6; ++m) {
        Av[m] = x * Av[m - 1] - y * Bv[m - 1];
        Bv[m] = x * Bv[m - 1] + y * Av[m - 1];
    }

    // Legendre state: value + dz only (dr2 via Euler identity)
    float P1v[7], P1z[7], P2v[7], P2z[7];
#pragma unroll
    for (int mm = 0; mm < 7; ++mm) {
        P1v[mm] = 0.f; P1z[mm] = 0.f; P2v[mm] = 0.f; P2z[mm] = 0.f;
    }

    const uint32_t sliceB = (uint32_t)N * 12u;          // bytes per (i,k,l) slice
    const uint32_t j0b    = (uint32_t)j0 * 12u;
    const uint32_t remB   = (uint32_t)(min(256, N - j0)) * 12u;
    char* const outB = (char*)out;
    const int tid3 = (int)threadIdx.x * 3;

#pragma unroll 1
    for (int l = 0; l <= LMAXV; ++l) {
        float S[NSZ], Tx[NSZ], Ty[NSZ], Tz[NSZ];
#pragma unroll
        for (int k = 0; k < NSZ; ++k) { S[k] = 0.0f; Tx[k] = 0.0f; Ty[k] = 0.0f; Tz[k] = 0.0f; }

        const float lf  = (float)l;
        const float a2l = 2.0f * lf - 1.0f;
        const float dfl = DFACT[l];

#pragma unroll
        for (int mm = 0; mm <= 6; ++mm) {
            if (mm <= l) {   // uniform scalar branch
                const float b  = lf + (float)(mm - 1);
                const float ic = ICT.v[l][mm];
                float pv = (a2l * z * P1v[mm] - b * r2 * P2v[mm]) * ic;
                float pz = (a2l * (P1v[mm] + z * P1z[mm]) - b * r2 * P2z[mm]) * ic;
                if (mm == l) pv = dfl;
                // Euler: z*Pz + 2 r2*Pr = (l-mm)*Pv  =>  Pr = ((l-mm)Pv - z Pz)/(2 r2)
                const float pr = ((lf - (float)mm) * pv - z * pz) * inv2r2;
                P2v[mm] = P1v[mm]; P2z[mm] = P1z[mm];
                P1v[mm] = pv; P1z[mm] = pz;

                const float c0  = CNL.v[l][mm];
                const float cp  = c0 * pv;
                const float prx = c0 * 2.0f * pr;
                const float gz  = c0 * pz + prx * z;
                const float pmv = cp * (float)mm;      // cp * m  (analyticity factor)
                const int  mp  = (mm > 0) ? mm - 1 : 0;

                const float ReV = cp * Av[mm];
                const float ReX = prx * x * Av[mm] + pmv * Av[mp];
                const float ReG = prx * y * Av[mm] - pmv * Bv[mp];
                const float ReZ = gz * Av[mm];
#pragma unroll
                for (int k = 0; k < NSZ; ++k) {
                    const float cc = sRe[l][mm][k];
                    S[k]  += cc * ReV;
                    Tx[k] += cc * ReX;
                    Ty[k] += cc * ReG;
                    Tz[k] += cc * ReZ;
                }
                if (mm >= 1) {
                    const float ImV = cp * Bv[mm];
                    const float ImX = prx * x * Bv[mm] + pmv * Bv[mp];
                    const float ImG = prx * y * Bv[mm] + pmv * Av[mp];
                    const float ImZ = gz * Bv[mm];
#pragma unroll
                    for (int k = 0; k < NSZ; ++k) {
                        const float cc = sIm[l][mm][k];
                        S[k]  += cc * ImV;
                        Tx[k] += cc * ImX;
                        Ty[k] += cc * ImG;
                        Tz[k] += cc * ImZ;
                    }
                }
            }
        }

        // stage + cooperative store, 3 groups of 12 slices
        const uint32_t lbase = 1008u + (uint32_t)l * sliceB + j0b;
        const uint32_t ikstride = 7u * sliceB;          // (i,k) pair stride in bytes
#pragma unroll
        for (int g = 0; g < 3; ++g) {
#pragma unroll
            for (int sl = 0; sl < 12; ++sl) {
                const int s = g * 12 + sl;
                const int i = s / 6, k = s % 6;
                const int a = (i < k) ? i : k;         // canonical: mirrors bit-identical
                const int c = (i < k) ? k : i;
                const float gg = dfi[a] * S[c] + dfi[c] * S[a];
                const float ox = ux * gg + f[a] * Tx[c] + f[c] * Tx[a];
                const float oy = uy * gg + f[a] * Ty[c] + f[c] * Ty[a];
                const float oz = uz * gg + f[a] * Tz[c] + f[c] * Tz[a];
                stage[sl][tid3 + 0] = ox;
                stage[sl][tid3 + 1] = oy;
                stage[sl][tid3 + 2] = oz;
            }
            barrier_lds();
            // cooperative write: 12 slices x 3072B, 16B lanes (full-line dwordx4)
#pragma unroll
            for (int it = 0; it < 9; ++it) {
                const int slot = it * 256 + (int)threadIdx.x;
                const int sl   = slot / 192;
                const int pos  = slot - sl * 192;
                const uint32_t boff = (uint32_t)pos << 4;
                if (boff < remB) {
                    const int s = g * 12 + sl;
                    float4v v = *(const float4v*)&stage[sl][pos << 2];
                    *(float4v*)(outB + lbase + (uint32_t)s * ikstride + boff) = v;
                }
            }
            barrier_lds();
        }
    }
}

// ---------------------------------------------------------------------------
extern "C" void kernel_launch(void* const* d_in, const int* in_sizes, int n_in,
                              void* d_out, int out_size, void* d_ws, size_t ws_size,
                              hipStream_t stream) {
    const float* coo = (const float*)d_in[0];
    float* out = (float*)d_out;
    float* cws = (float*)d_ws;
    const int N = in_sizes[0] / 3;

    hipLaunchKernelGGL(k_zero, dim3(1), dim3(320), 0, stream, cws);
    hipLaunchKernelGGL(k_creduce, dim3(128, 6), dim3(256), 0, stream, coo, cws, N);
    hipLaunchKernelGGL(k_p, dim3(1), dim3(256), 0, stream, cws, out);
    const int nb = (N + 255) / 256;
    hipLaunchKernelGGL(k_dp, dim3(nb), dim3(256), 0, stream, coo, cws, out, N, nb);
}